// Round 7
// baseline (302.586 us; speedup 1.0000x reference)
//
#include <hip/hip_runtime.h>
#include <math.h>

#define NB 2
#define LL 4096
#define HH 1024
#define DD 64
#define CHK 64
#define NCH 64            /* LL/CHK */
#define BLROWS (NB*LL)    /* 8192 */
#define NCHT (NB*NCH)     /* 128 total chunks */
#define GAMMA 0.96875f

typedef _Float16 f16x8 __attribute__((ext_vector_type(8)));
typedef _Float16 f16x4 __attribute__((ext_vector_type(4)));
typedef float    f32x4 __attribute__((ext_vector_type(4)));

#define WCH 12288   /* W frag layout: [16 kchunks][12 ct][2 kt][64 lanes][8] */
#define NBLK 512

// DIY grid barrier: per-block flag, monotone magic (poison 0xAAAAAAAA < MAGIC).
// All 512 blocks are co-resident by construction (launch_bounds(256,2) => VGPR
// <=256 => >=2 waves/SIMD => >=2 blocks/CU; LDS 35.7KB => 4/CU; 2*256 >= 512).
__device__ __forceinline__ void grid_bar(unsigned* flags, unsigned phase,
                                         int bid, int tid)
{
    __syncthreads();
    const unsigned tgt = 0xBB000000u + phase;
    if (tid == 0)
        __hip_atomic_store(&flags[bid], tgt, __ATOMIC_RELEASE,
                           __HIP_MEMORY_SCOPE_AGENT);
    long long guard = 0;
    while (__hip_atomic_load(&flags[tid], __ATOMIC_ACQUIRE,
                             __HIP_MEMORY_SCOPE_AGENT) < tgt &&
           guard < 30000000LL) { __builtin_amdgcn_s_sleep(1); ++guard; }
    while (__hip_atomic_load(&flags[tid + 256], __ATOMIC_ACQUIRE,
                             __HIP_MEMORY_SCOPE_AGENT) < tgt &&
           guard < 30000000LL) { __builtin_amdgcn_s_sleep(1); ++guard; }
    __syncthreads();
}

__global__ __launch_bounds__(256, 2) void retention_all(
    const float* __restrict__ X, const float* __restrict__ WQ,
    const float* __restrict__ WK, const float* __restrict__ WV,
    _Float16* __restrict__ Whg, _Float16* __restrict__ Wlg,
    _Float16* __restrict__ Qr, _Float16* __restrict__ Kr,
    _Float16* __restrict__ Vr, float* __restrict__ U,
    unsigned* __restrict__ flags, float* __restrict__ out)
{
    __shared__ __align__(16) unsigned char smraw[35648];
    const int tid = threadIdx.x;
    const int bid = blockIdx.x;

    // ============================ P0: prep W ==============================
    {
        const unsigned t = bid * 256 + tid;
        if (t < 24576u) {
            const unsigned kchunk = t / 1536u;
            const unsigned s = t - kchunk * 1536u;
            const int ct2  = s >> 6;
            const int lane = s & 63;
            const int n16  = ct2 >> 1;
            const int kt   = ct2 & 1;
            const int quad = lane >> 4;
            const int n    = n16 * 16 + (lane & 15);
            const int k0   = (int)kchunk * 64 + kt * 32 + quad * 8;
            const int m    = n >> 6;
            const int d    = n & 63;
            const float* Wm = (m == 0) ? WQ : (m == 1) ? WK : WV;
            f16x8 hv, lv;
#pragma unroll
            for (int j = 0; j < 8; ++j) {
                const float x = Wm[(size_t)(k0 + j) * DD + d] * 1024.f;
                const _Float16 h = (_Float16)x;
                hv[j] = h;
                lv[j] = (_Float16)(x - (float)h);
            }
            *(f16x8*)&Whg[(size_t)t * 8] = hv;
            *(f16x8*)&Wlg[(size_t)t * 8] = lv;
        }
    }
    grid_bar(flags, 1, bid, tid);

    // ============================ P1: projection ==========================
    // 512 blocks: rowgroup = bid>>1 (32 rows), colhalf = bid&1 (96 cols).
    // Wave w: rowtile rt=w&1, coltiles (w>>1)*3..+2 (local). LDS-staged W.
    {
        _Float16* lds = (_Float16*)smraw;
        _Float16* Xh = lds;              // 2048 halfs
        _Float16* Xl = lds + 2048;       // 2048
        _Float16* Wh = lds + 4096;       // 6144 (6 ct x 2 kt x 64 x 8)
        _Float16* Wl = lds + 10240;      // 6144

        const int wv   = tid >> 6;
        const int lane = tid & 63;
        const int quad = lane >> 4;
        const int l15  = lane & 15;
        const int r0   = (bid >> 1) * 32;
        const int cb6  = (bid & 1) * 6;
        const int rt   = wv & 1;
        const int ct3  = (wv >> 1) * 3;

        const int xrow = tid >> 3;              // 0..31
        const int xk8  = (tid & 7) * 8;         // 0..56
        const int xslot = (((xrow >> 4) * 2 + (xk8 >> 5)) * 64 +
                           ((xk8 >> 3) & 3) * 16 + (xrow & 15)) * 8;

        f32x4 acc[3];
#pragma unroll
        for (int i = 0; i < 3; ++i) acc[i] = (f32x4){0.f, 0.f, 0.f, 0.f};

        float4 pxa, pxb;
        f16x8  pwh[3], pwl6[3];
        {   // prefetch chunk 0 (W ready after barrier 1)
            const float* xp = &X[(size_t)(r0 + xrow) * HH + xk8];
            pxa = *(const float4*)&xp[0];
            pxb = *(const float4*)&xp[4];
#pragma unroll
            for (int i = 0; i < 3; ++i) {
                const int s = tid + i * 256;            // 0..767
                const int ctl = s >> 7, kt = (s >> 6) & 1, ln = s & 63;
                const size_t off = (size_t)(((cb6 + ctl) * 2 + kt) * 64 + ln) * 8;
                pwh[i]  = *(const f16x8*)&Whg[off];
                pwl6[i] = *(const f16x8*)&Wlg[off];
            }
        }

        for (int ch = 0; ch < 16; ++ch) {
            __syncthreads();
            {
                const float xv[8] = {pxa.x, pxa.y, pxa.z, pxa.w,
                                     pxb.x, pxb.y, pxb.z, pxb.w};
                f16x8 hv, lv;
#pragma unroll
                for (int e = 0; e < 8; ++e) {
                    const _Float16 h = (_Float16)xv[e];
                    hv[e] = h;
                    lv[e] = (_Float16)(xv[e] - (float)h);
                }
                *(f16x8*)&Xh[xslot] = hv;
                *(f16x8*)&Xl[xslot] = lv;
#pragma unroll
                for (int i = 0; i < 3; ++i) {
                    *(f16x8*)&Wh[(tid + i * 256) * 8] = pwh[i];
                    *(f16x8*)&Wl[(tid + i * 256) * 8] = pwl6[i];
                }
            }
            __syncthreads();
            if (ch + 1 < 16) {
                const float* xp = &X[(size_t)(r0 + xrow) * HH + (ch + 1) * 64 + xk8];
                pxa = *(const float4*)&xp[0];
                pxb = *(const float4*)&xp[4];
                const size_t cb = (size_t)(ch + 1) * WCH;
#pragma unroll
                for (int i = 0; i < 3; ++i) {
                    const int s = tid + i * 256;
                    const int ctl = s >> 7, kt = (s >> 6) & 1, ln = s & 63;
                    const size_t off = cb +
                        (size_t)(((cb6 + ctl) * 2 + kt) * 64 + ln) * 8;
                    pwh[i]  = *(const f16x8*)&Whg[off];
                    pwl6[i] = *(const f16x8*)&Wlg[off];
                }
            }
#pragma unroll
            for (int kt = 0; kt < 2; ++kt) {
                const f16x8 aH = *(const f16x8*)&Xh[((rt * 2 + kt) * 64 + lane) * 8];
                const f16x8 aL = *(const f16x8*)&Xl[((rt * 2 + kt) * 64 + lane) * 8];
#pragma unroll
                for (int cj = 0; cj < 3; ++cj) {
                    const int ctl = ct3 + cj;
                    const f16x8 bh = *(const f16x8*)&Wh[((ctl * 2 + kt) * 64 + lane) * 8];
                    const f16x8 bl = *(const f16x8*)&Wl[((ctl * 2 + kt) * 64 + lane) * 8];
                    acc[cj] = __builtin_amdgcn_mfma_f32_16x16x32_f16(aH, bh, acc[cj], 0, 0, 0);
                    acc[cj] = __builtin_amdgcn_mfma_f32_16x16x32_f16(aH, bl, acc[cj], 0, 0, 0);
                    acc[cj] = __builtin_amdgcn_mfma_f32_16x16x32_f16(aL, bh, acc[cj], 0, 0, 0);
                }
            }
        }

        // epilogue: descale + xPos (per-chunk renormalized scale), fp16 out
#pragma unroll
        for (int cj = 0; cj < 3; ++cj) {
            const int ctg = cb6 + ct3 + cj;
            const f32x4 v = acc[cj];
            const int col = ctg * 16 + l15;
            const int mat = ctg >> 2;            // 0=Q 1=K 2=V
            const int d   = col & 63;
            if (mat < 2) {
                const int i2 = d >> 1;
                const float sv   = (2.f * (float)i2 + 25.6f) / 89.6f;
                const float l2sv = log2f(sv);
                const float ifr  = exp2f(-13.28771237954945f * ((float)i2 / 32.f));
                const float sgn  = (mat == 0) ? 1.f : -1.f;
                _Float16* dst = (mat == 0) ? Qr : Kr;
#pragma unroll
                for (int r = 0; r < 4; ++r) {
                    const int row = r0 + rt * 16 + quad * 4 + r;
                    const float val = v[r] * (1.f / 1024.f);
                    const float p = __shfl_xor(val, 1, 64);
                    const float pf  = (float)(row & (LL - 1));
                    const float pfs = (float)(row & 63);
                    const float scl = exp2f(sgn * (pfs * (1.f / 512.f)) * l2sv);
                    float s, c;
                    sincosf(pf * ifr, &s, &c);
                    s *= scl; c *= scl;
                    const float o = ((col & 1) == 0) ? val * c - p * s
                                                     : val * c + p * s;
                    dst[(size_t)row * DD + d] = (_Float16)o;
                }
            } else {
#pragma unroll
                for (int r = 0; r < 4; ++r) {
                    const int row = r0 + rt * 16 + quad * 4 + r;
                    Vr[(size_t)row * DD + d] = (_Float16)(v[r] * (1.f / 1024.f));
                }
            }
        }
    }
    grid_bar(flags, 2, bid, tid);

    // ============================ P2: chunk KV ============================
    if (bid < 256) {
        _Float16* Kl  = (_Float16*)smraw;            // 8192 B
        _Float16* Vl  = (_Float16*)(smraw + 8192);   // 4096 B
        float*    pwd = (float*)(smraw + 12288);     // 256 B
        const int chunk = bid >> 1;
        const int dph   = (bid & 1) * 32;
        const size_t rbase = (size_t)chunk * CHK * DD;
        const float l2g = log2f(GAMMA);

        if (tid < 64) pwd[tid] = exp2f((float)(63 - tid) * l2g);
        {
            const int row = tid >> 2;
            const int c0  = (tid & 3) * 16;
            *(f16x8*)&Kl[row * 64 + c0]     = *(const f16x8*)&Kr[rbase + (size_t)row * DD + c0];
            *(f16x8*)&Kl[row * 64 + c0 + 8] = *(const f16x8*)&Kr[rbase + (size_t)row * DD + c0 + 8];
            const int c1 = (tid & 3) * 8;
            *(f16x8*)&Vl[row * 32 + c1] = *(const f16x8*)&Vr[rbase + (size_t)row * DD + dph + c1];
        }
        __syncthreads();
        const int dgr = tid >> 4;
        const int dc  = tid & 15;
        float a[4][2] = {{0,0},{0,0},{0,0},{0,0}};
#pragma unroll 8
        for (int j = 0; j < CHK; ++j) {
            const f16x4 kh = *(const f16x4*)&Kl[j * 64 + dgr * 4];
            const float w  = pwd[j];
            const float v0 = (float)Vl[j * 32 + dc * 2]     * w;
            const float v1 = (float)Vl[j * 32 + dc * 2 + 1] * w;
            const float k0 = (float)kh[0], k1 = (float)kh[1];
            const float k2 = (float)kh[2], k3 = (float)kh[3];
            a[0][0] += k0 * v0; a[0][1] += k0 * v1;
            a[1][0] += k1 * v0; a[1][1] += k1 * v1;
            a[2][0] += k2 * v0; a[2][1] += k2 * v1;
            a[3][0] += k3 * v0; a[3][1] += k3 * v1;
        }
#pragma unroll
        for (int r = 0; r < 4; ++r) {
            *(float2*)&U[((size_t)chunk * DD + dgr * 4 + r) * DD + dph + dc * 2] =
                make_float2(a[r][0], a[r][1]);
        }
    }
    grid_bar(flags, 3, bid, tid);

    // ============================ P3: output ==============================
    if (bid < 256) {
        _Float16* Sb  = (_Float16*)smraw;            // 32*136 f16 = 8704 B
        _Float16* Vl  = (_Float16*)(smraw + 8704);   // 64*72 f16 = 9216 B
        float*    Tl  = (float*)(smraw + 17920);     // 64*68 f32 = 17408 B
        float*    pwl = (float*)(smraw + 35328);     // 65 f32

        const int chunk = bid >> 1;
        const int nh    = (bid & 1) * 32;
        const int w     = tid >> 6;
        const int lane  = tid & 63;
        const int quad  = lane >> 4;
        const int l15   = lane & 15;
        const int mtile = w >> 1;
        const int npair = (w & 1) * 2;
        const size_t rowbase = (size_t)chunk * CHK + nh;
        const float l2g = log2f(GAMMA);

        if (tid < 65) pwl[tid] = exp2f((float)tid * l2g);

        {   // stage V rows
            const int row = tid >> 2;
            const int c0  = (tid & 3) * 16;
            const size_t rb = (size_t)chunk * CHK * DD;
            *(f16x8*)&Vl[row * 72 + c0]     = *(const f16x8*)&Vr[rb + (size_t)row * DD + c0];
            *(f16x8*)&Vl[row * 72 + c0 + 8] = *(const f16x8*)&Vr[rb + (size_t)row * DD + c0 + 8];
        }
        {   // build T~ from 8 preceding U chunks
            const int d  = tid >> 2;
            const int dq = (tid & 3) * 16;
            const int cloc = chunk & 63;
            const float sv = (2.f * (float)(d >> 1) + 25.6f) / 89.6f;
            const float l2sv = log2f(sv);
            float acc[16];
#pragma unroll
            for (int i = 0; i < 16; ++i) acc[i] = 0.f;
            for (int dl = 1; dl <= 8; ++dl) {
                if (dl <= cloc) {
                    const float f = exp2f(64.f * (float)(dl - 1) * l2g +
                                          0.125f * (float)dl * l2sv);
                    const float* up = &U[((size_t)(chunk - dl) * DD + d) * DD + dq];
#pragma unroll
                    for (int i4 = 0; i4 < 4; ++i4) {
                        const float4 u = *(const float4*)&up[i4 * 4];
                        acc[i4 * 4 + 0] += f * u.x; acc[i4 * 4 + 1] += f * u.y;
                        acc[i4 * 4 + 2] += f * u.z; acc[i4 * 4 + 3] += f * u.w;
                    }
                }
            }
#pragma unroll
            for (int i = 0; i < 16; ++i) Tl[d * 68 + dq + i] = acc[i];
        }

        f16x8 aQ[2], bK[2][2];
#pragma unroll
        for (int ks = 0; ks < 2; ++ks)
            aQ[ks] = *(const f16x8*)&Qr[(rowbase + mtile * 16 + l15) * DD +
                                        ks * 32 + quad * 8];
#pragma unroll
        for (int nt = 0; nt < 2; ++nt)
#pragma unroll
            for (int ks = 0; ks < 2; ++ks)
                bK[nt][ks] = *(const f16x8*)&Kr[((size_t)chunk * CHK +
                                                (npair + nt) * 16 + l15) * DD +
                                                ks * 32 + quad * 8];
        __syncthreads();   // Vl, Tl, pwl ready

        f32x4 sA[2] = {(f32x4){0.f,0.f,0.f,0.f}, (f32x4){0.f,0.f,0.f,0.f}};
#pragma unroll
        for (int nt = 0; nt < 2; ++nt)
#pragma unroll
            for (int ks = 0; ks < 2; ++ks)
                sA[nt] = __builtin_amdgcn_mfma_f32_16x16x32_f16(aQ[ks], bK[nt][ks],
                                                                sA[nt], 0, 0, 0);
#pragma unroll
        for (int nt = 0; nt < 2; ++nt) {
            const int m = (npair + nt) * 16 + l15;
#pragma unroll
            for (int r = 0; r < 4; ++r) {
                const int nl = mtile * 16 + quad * 4 + r;
                const int n64 = nh + nl;
                const float val = (n64 >= m) ? sA[nt][r] * pwl[n64 - m] : 0.f;
                Sb[nl * 136 + m] = (_Float16)val;
            }
        }
        if ((w & 1) == 0) {
            const float g = pwl[nh + mtile * 16 + l15 + 1];
#pragma unroll
            for (int ks = 0; ks < 2; ++ks) {
                f16x8 qv;
#pragma unroll
                for (int j = 0; j < 8; ++j)
                    qv[j] = (_Float16)((float)aQ[ks][j] * g);
                *(f16x8*)&Sb[(mtile * 16 + l15) * 136 + 64 + ks * 32 + quad * 8] = qv;
            }
        }
        __syncthreads();

        f32x4 oA[2] = {(f32x4){0.f,0.f,0.f,0.f}, (f32x4){0.f,0.f,0.f,0.f}};
#pragma unroll
        for (int ks = 0; ks < 4; ++ks) {
            const f16x8 aS = *(const f16x8*)&Sb[(mtile * 16 + l15) * 136 +
                                                ks * 32 + quad * 8];
#pragma unroll
            for (int nt = 0; nt < 2; ++nt) {
                const int dp = (npair + nt) * 16 + l15;
                f16x8 bV;
                if (ks < 2) {
#pragma unroll
                    for (int j = 0; j < 8; ++j)
                        bV[j] = Vl[(ks * 32 + quad * 8 + j) * 72 + dp];
                } else {
#pragma unroll
                    for (int j = 0; j < 8; ++j)
                        bV[j] = (_Float16)Tl[((ks - 2) * 32 + quad * 8 + j) * 68 + dp];
                }
                oA[nt] = __builtin_amdgcn_mfma_f32_16x16x32_f16(aS, bV, oA[nt], 0, 0, 0);
            }
        }
#pragma unroll
        for (int nt = 0; nt < 2; ++nt)
#pragma unroll
            for (int r = 0; r < 4; ++r)
                out[(rowbase + mtile * 16 + quad * 4 + r) * DD +
                    (npair + nt) * 16 + l15] = oA[nt][r];
    }
}

// ---------------------------------------------------------------------------
extern "C" void kernel_launch(void* const* d_in, const int* in_sizes, int n_in,
                              void* d_out, int out_size, void* d_ws, size_t ws_size,
                              hipStream_t stream)
{
    const float* X  = (const float*)d_in[0];
    const float* WQ = (const float*)d_in[1];
    const float* WK = (const float*)d_in[2];
    const float* WV = (const float*)d_in[3];
    float* outp = (float*)d_out;

    _Float16* Whg = (_Float16*)d_ws;                 // 196608 h
    _Float16* Wlg = Whg + 196608;                    // 196608 h
    _Float16* Qr  = Wlg + 196608;                    // 524288 h
    _Float16* Kr  = Qr + (size_t)BLROWS * DD;        // 524288 h
    _Float16* Vr  = Kr + (size_t)BLROWS * DD;        // 524288 h
    float*    U   = (float*)(Vr + (size_t)BLROWS * DD);   // 524288 f
    unsigned* flags = (unsigned*)(U + (size_t)NCHT * DD * DD);  // 512 u32
    // total ~6.0 MB

    hipLaunchKernelGGL(retention_all, dim3(NBLK), dim3(256), 0, stream,
                       X, WQ, WK, WV, Whg, Wlg, Qr, Kr, Vr, U, flags, outp);
}

// Round 8
// 113.124 us; speedup vs baseline: 2.6748x; 2.6748x over previous
//
#include <hip/hip_runtime.h>
#include <math.h>

#define NB 2
#define LL 4096
#define HH 1024
#define DD 64
#define CHK 64
#define NCH 64            /* LL/CHK */
#define BLROWS (NB*LL)    /* 8192 */
#define NCHT (NB*NCH)     /* 128 total chunks */
#define GAMMA 0.96875f

typedef _Float16 f16x8 __attribute__((ext_vector_type(8)));
typedef _Float16 f16x4 __attribute__((ext_vector_type(4)));
typedef float    f32x4 __attribute__((ext_vector_type(4)));

#define WCH 12288   /* W frag layout: [16 kchunks][12 ct][2 kt][64 lanes][8] */

// ---------------------------------------------------------------------------
// Kernel 0: split W (scaled 2^10) into fp16 hi/lo, fragment order.
// grid 96 x 256 (24576 f16x8 slots), coalesced stores.
// ---------------------------------------------------------------------------
__global__ __launch_bounds__(256) void prep_w(
    const float* __restrict__ WQ, const float* __restrict__ WK,
    const float* __restrict__ WV, _Float16* __restrict__ Whg,
    _Float16* __restrict__ Wlg)
{
    const unsigned t = blockIdx.x * 256 + threadIdx.x;   // 0..24575
    const unsigned kchunk = t / 1536u;
    const unsigned s = t - kchunk * 1536u;
    const int ct2  = s >> 6;            // (n16)*2 + kt
    const int lane = s & 63;
    const int n16  = ct2 >> 1;
    const int kt   = ct2 & 1;
    const int quad = lane >> 4;
    const int n    = n16 * 16 + (lane & 15);
    const int k0   = (int)kchunk * 64 + kt * 32 + quad * 8;
    const int m    = n >> 6;
    const int d    = n & 63;
    const float* Wm = (m == 0) ? WQ : (m == 1) ? WK : WV;
    f16x8 hv, lv;
#pragma unroll
    for (int j = 0; j < 8; ++j) {
        const float x = Wm[(size_t)(k0 + j) * DD + d] * 1024.f;
        const _Float16 h = (_Float16)x;
        hv[j] = h;
        lv[j] = (_Float16)(x - (float)h);
    }
    *(f16x8*)&Whg[(size_t)t * 8] = hv;
    *(f16x8*)&Wlg[(size_t)t * 8] = lv;
}

// ---------------------------------------------------------------------------
// Kernel 1: MFMA projection (fp16 split-3) + xPos epilogue.
// grid 768 = (rowgroup 256) x (colthird 3), 256 thr (4 waves) -> 3 blocks/CU.
// Block = 32 rows x 64 cols (4 coltiles). Wave w: rowtile rt=w&1, coltiles
// (w>>1)*2 .. +1. LDS: Xh/Xl 4K halfs + Wh/Wl 8K halfs = 24.5 KB.
// Register-prefetch pipelined (load ch+1 while computing ch).
// ---------------------------------------------------------------------------
__global__ __launch_bounds__(256) void proj_mfma(
    const float* __restrict__ X, const _Float16* __restrict__ Whg,
    const _Float16* __restrict__ Wlg, _Float16* __restrict__ Qr,
    _Float16* __restrict__ Kr, _Float16* __restrict__ Vr)
{
    __shared__ __align__(16) _Float16 lds[12288];
    _Float16* Xh = lds;              // 2048 halfs
    _Float16* Xl = lds + 2048;       // 2048
    _Float16* Wh = lds + 4096;       // 4096 (4 ct x 2 kt x 64 x 8)
    _Float16* Wl = lds + 8192;       // 4096

    const int tid  = threadIdx.x;
    const int wv   = tid >> 6;
    const int lane = tid & 63;
    const int quad = lane >> 4;
    const int l15  = lane & 15;
    const int r0   = (blockIdx.x & 255) * 32;
    const int cb4  = (blockIdx.x >> 8) * 4;      // global coltile base (0,4,8)
    const int rt   = wv & 1;
    const int cp   = (wv >> 1) * 2;              // local coltile pair base

    // staging coords
    const int xrow = tid >> 3;              // 0..31
    const int xk8  = (tid & 7) * 8;         // 0..56
    const int xslot = (((xrow >> 4) * 2 + (xk8 >> 5)) * 64 +
                       ((xk8 >> 3) & 3) * 16 + (xrow & 15)) * 8;

    f32x4 acc[2];
    acc[0] = (f32x4){0.f, 0.f, 0.f, 0.f};
    acc[1] = (f32x4){0.f, 0.f, 0.f, 0.f};

    float4 pxa, pxb;
    f16x8  pwh[2], pwl2[2];
    {   // prefetch chunk 0
        const float* xp = &X[(size_t)(r0 + xrow) * HH + xk8];
        pxa = *(const float4*)&xp[0];
        pxb = *(const float4*)&xp[4];
#pragma unroll
        for (int i = 0; i < 2; ++i) {
            const int s = tid + i * 256;            // 0..511
            const int ctl = s >> 7, kt = (s >> 6) & 1, ln = s & 63;
            const size_t off = (size_t)(((cb4 + ctl) * 2 + kt) * 64 + ln) * 8;
            pwh[i]  = *(const f16x8*)&Whg[off];
            pwl2[i] = *(const f16x8*)&Wlg[off];
        }
    }

    for (int ch = 0; ch < 16; ++ch) {
        __syncthreads();
        {   // commit prefetched chunk to LDS
            const float xv[8] = {pxa.x, pxa.y, pxa.z, pxa.w,
                                 pxb.x, pxb.y, pxb.z, pxb.w};
            f16x8 hv, lv;
#pragma unroll
            for (int e = 0; e < 8; ++e) {
                const _Float16 h = (_Float16)xv[e];
                hv[e] = h;
                lv[e] = (_Float16)(xv[e] - (float)h);
            }
            *(f16x8*)&Xh[xslot] = hv;
            *(f16x8*)&Xl[xslot] = lv;
#pragma unroll
            for (int i = 0; i < 2; ++i) {
                *(f16x8*)&Wh[(tid + i * 256) * 8] = pwh[i];
                *(f16x8*)&Wl[(tid + i * 256) * 8] = pwl2[i];
            }
        }
        __syncthreads();
        if (ch + 1 < 16) {   // prefetch next chunk (overlaps compute)
            const float* xp = &X[(size_t)(r0 + xrow) * HH + (ch + 1) * 64 + xk8];
            pxa = *(const float4*)&xp[0];
            pxb = *(const float4*)&xp[4];
            const size_t cb = (size_t)(ch + 1) * WCH;
#pragma unroll
            for (int i = 0; i < 2; ++i) {
                const int s = tid + i * 256;
                const int ctl = s >> 7, kt = (s >> 6) & 1, ln = s & 63;
                const size_t off = cb +
                    (size_t)(((cb4 + ctl) * 2 + kt) * 64 + ln) * 8;
                pwh[i]  = *(const f16x8*)&Whg[off];
                pwl2[i] = *(const f16x8*)&Wlg[off];
            }
        }
#pragma unroll
        for (int kt = 0; kt < 2; ++kt) {
            const f16x8 aH = *(const f16x8*)&Xh[((rt * 2 + kt) * 64 + lane) * 8];
            const f16x8 aL = *(const f16x8*)&Xl[((rt * 2 + kt) * 64 + lane) * 8];
#pragma unroll
            for (int cj = 0; cj < 2; ++cj) {
                const int ctl = cp + cj;
                const f16x8 bh = *(const f16x8*)&Wh[((ctl * 2 + kt) * 64 + lane) * 8];
                const f16x8 bl = *(const f16x8*)&Wl[((ctl * 2 + kt) * 64 + lane) * 8];
                acc[cj] = __builtin_amdgcn_mfma_f32_16x16x32_f16(aH, bh, acc[cj], 0, 0, 0);
                acc[cj] = __builtin_amdgcn_mfma_f32_16x16x32_f16(aH, bl, acc[cj], 0, 0, 0);
                acc[cj] = __builtin_amdgcn_mfma_f32_16x16x32_f16(aL, bh, acc[cj], 0, 0, 0);
            }
        }
    }

    // ---- epilogue: descale + xPos (per-chunk renormalized scale), fp16 out
#pragma unroll
    for (int cj = 0; cj < 2; ++cj) {
        const int ctg = cb4 + cp + cj;
        const f32x4 v = acc[cj];
        const int col = ctg * 16 + l15;
        const int mat = ctg >> 2;            // 0=Q 1=K 2=V
        const int d   = col & 63;
        if (mat < 2) {
            const int i2 = d >> 1;
            const float sv   = (2.f * (float)i2 + 25.6f) / 89.6f;
            const float l2sv = log2f(sv);
            const float ifr  = exp2f(-13.28771237954945f * ((float)i2 / 32.f));
            const float sgn  = (mat == 0) ? 1.f : -1.f;
            _Float16* dst = (mat == 0) ? Qr : Kr;
#pragma unroll
            for (int r = 0; r < 4; ++r) {
                const int row = r0 + rt * 16 + quad * 4 + r;
                const float val = v[r] * (1.f / 1024.f);
                const float p = __shfl_xor(val, 1, 64);
                const float pf  = (float)(row & (LL - 1));   // abs pos
                const float pfs = (float)(row & 63);          // renorm
                const float scl = exp2f(sgn * (pfs * (1.f / 512.f)) * l2sv);
                float s, c;
                sincosf(pf * ifr, &s, &c);
                s *= scl; c *= scl;
                const float o = ((col & 1) == 0) ? val * c - p * s
                                                 : val * c + p * s;
                dst[(size_t)row * DD + d] = (_Float16)o;
            }
        } else {
#pragma unroll
            for (int r = 0; r < 4; ++r) {
                const int row = r0 + rt * 16 + quad * 4 + r;
                Vr[(size_t)row * DD + d] = (_Float16)(v[r] * (1.f / 1024.f));
            }
        }
    }
}

// ---------------------------------------------------------------------------
// Kernel 2: U~[chunk][d][d'] = sum_j g^(63-j) K~[j][d] V[j][d']  (fp32 out)
// grid 256 = (chunk 128) x (d'-half 2), 256 thr.
// ---------------------------------------------------------------------------
__global__ __launch_bounds__(256) void chunk_kv(
    const _Float16* __restrict__ Kr, const _Float16* __restrict__ Vr,
    float* __restrict__ U)
{
    __shared__ _Float16 Kl[64 * 64];
    __shared__ _Float16 Vl[64 * 32];
    __shared__ float pwd[64];
    const int tid   = threadIdx.x;
    const int bc    = blockIdx.x;
    const int chunk = bc >> 1;
    const int dph   = (bc & 1) * 32;
    const size_t rbase = (size_t)chunk * CHK * DD;
    const float l2g = log2f(GAMMA);

    if (tid < 64) pwd[tid] = exp2f((float)(63 - tid) * l2g);
    {
        const int row = tid >> 2;
        const int c0  = (tid & 3) * 16;
        *(f16x8*)&Kl[row * 64 + c0]     = *(const f16x8*)&Kr[rbase + (size_t)row * DD + c0];
        *(f16x8*)&Kl[row * 64 + c0 + 8] = *(const f16x8*)&Kr[rbase + (size_t)row * DD + c0 + 8];
        const int c1 = (tid & 3) * 8;
        *(f16x8*)&Vl[row * 32 + c1] = *(const f16x8*)&Vr[rbase + (size_t)row * DD + dph + c1];
    }
    __syncthreads();
    const int dgr = tid >> 4;
    const int dc  = tid & 15;
    float a[4][2] = {{0,0},{0,0},{0,0},{0,0}};
#pragma unroll 8
    for (int j = 0; j < CHK; ++j) {
        const f16x4 kh = *(const f16x4*)&Kl[j * 64 + dgr * 4];
        const float w  = pwd[j];
        const float v0 = (float)Vl[j * 32 + dc * 2]     * w;
        const float v1 = (float)Vl[j * 32 + dc * 2 + 1] * w;
        const float k0 = (float)kh[0], k1 = (float)kh[1];
        const float k2 = (float)kh[2], k3 = (float)kh[3];
        a[0][0] += k0 * v0; a[0][1] += k0 * v1;
        a[1][0] += k1 * v0; a[1][1] += k1 * v1;
        a[2][0] += k2 * v0; a[2][1] += k2 * v1;
        a[3][0] += k3 * v0; a[3][1] += k3 * v1;
    }
#pragma unroll
    for (int r = 0; r < 4; ++r) {
        *(float2*)&U[((size_t)chunk * DD + dgr * 4 + r) * DD + dph + dc * 2] =
            make_float2(a[r][0], a[r][1]);
    }
}

// ---------------------------------------------------------------------------
// Kernel 3: chunk output with in-LDS T-build.
//   T~_c = sum_{D=1..8} g^{64(D-1)} sv_d^{D/8} U~[c-D]   (in LDS, fp32)
//   phase A: S = mask(Q~ K~^T); S2 = [S | g^{n'+1} Q~] -> LDS (A-frag order)
//   phase B: out = S2 @ [V ; T~]   (B-frags gathered from LDS)
// grid 256 = (chunk 128) x (n-half 2), 256 thr.
// ---------------------------------------------------------------------------
__global__ __launch_bounds__(256) void chunk_out(
    const _Float16* __restrict__ Qr, const _Float16* __restrict__ Kr,
    const _Float16* __restrict__ Vr, const float* __restrict__ U,
    float* __restrict__ out)
{
    __shared__ __align__(16) unsigned char smraw[35648];
    _Float16* Sb  = (_Float16*)smraw;            // 32*136 f16 = 8704 B
    _Float16* Vl  = (_Float16*)(smraw + 8704);   // 64*72 f16 = 9216 B
    float*    Tl  = (float*)(smraw + 17920);     // 64*68 f32 = 17408 B
    float*    pwl = (float*)(smraw + 35328);     // 65 f32

    const int tid   = threadIdx.x;
    const int bc    = blockIdx.x;
    const int chunk = bc >> 1;
    const int nh    = (bc & 1) * 32;
    const int w     = tid >> 6;
    const int lane  = tid & 63;
    const int quad  = lane >> 4;
    const int l15   = lane & 15;
    const int mtile = w >> 1;
    const int npair = (w & 1) * 2;
    const size_t rowbase = (size_t)chunk * CHK + nh;
    const float l2g = log2f(GAMMA);

    if (tid < 65) pwl[tid] = exp2f((float)tid * l2g);

    {   // stage V rows
        const int row = tid >> 2;
        const int c0  = (tid & 3) * 16;
        const size_t rb = (size_t)chunk * CHK * DD;
        *(f16x8*)&Vl[row * 72 + c0]     = *(const f16x8*)&Vr[rb + (size_t)row * DD + c0];
        *(f16x8*)&Vl[row * 72 + c0 + 8] = *(const f16x8*)&Vr[rb + (size_t)row * DD + c0 + 8];
    }
    {   // build T~ from 8 preceding U chunks
        const int d  = tid >> 2;
        const int dq = (tid & 3) * 16;
        const int cloc = chunk & 63;
        const float sv = (2.f * (float)(d >> 1) + 25.6f) / 89.6f;
        const float l2sv = log2f(sv);
        float acc[16];
#pragma unroll
        for (int i = 0; i < 16; ++i) acc[i] = 0.f;
        for (int dl = 1; dl <= 8; ++dl) {
            if (dl <= cloc) {
                const float f = exp2f(64.f * (float)(dl - 1) * l2g +
                                      0.125f * (float)dl * l2sv);
                const float* up = &U[((size_t)(chunk - dl) * DD + d) * DD + dq];
#pragma unroll
                for (int i4 = 0; i4 < 4; ++i4) {
                    const float4 u = *(const float4*)&up[i4 * 4];
                    acc[i4 * 4 + 0] += f * u.x; acc[i4 * 4 + 1] += f * u.y;
                    acc[i4 * 4 + 2] += f * u.z; acc[i4 * 4 + 3] += f * u.w;
                }
            }
        }
#pragma unroll
        for (int i = 0; i < 16; ++i) Tl[d * 68 + dq + i] = acc[i];
    }

    // global A/B frags for phase A
    f16x8 aQ[2], bK[2][2];
#pragma unroll
    for (int ks = 0; ks < 2; ++ks)
        aQ[ks] = *(const f16x8*)&Qr[(rowbase + mtile * 16 + l15) * DD +
                                    ks * 32 + quad * 8];
#pragma unroll
    for (int nt = 0; nt < 2; ++nt)
#pragma unroll
        for (int ks = 0; ks < 2; ++ks)
            bK[nt][ks] = *(const f16x8*)&Kr[((size_t)chunk * CHK +
                                            (npair + nt) * 16 + l15) * DD +
                                            ks * 32 + quad * 8];
    __syncthreads();   // Vl, Tl, pwl ready

    f32x4 sA[2] = {(f32x4){0.f,0.f,0.f,0.f}, (f32x4){0.f,0.f,0.f,0.f}};
#pragma unroll
    for (int nt = 0; nt < 2; ++nt)
#pragma unroll
        for (int ks = 0; ks < 2; ++ks)
            sA[nt] = __builtin_amdgcn_mfma_f32_16x16x32_f16(aQ[ks], bK[nt][ks],
                                                            sA[nt], 0, 0, 0);
    // mask + decay -> Sb (A-frag layout, fp16)
#pragma unroll
    for (int nt = 0; nt < 2; ++nt) {
        const int m = (npair + nt) * 16 + l15;
#pragma unroll
        for (int r = 0; r < 4; ++r) {
            const int nl = mtile * 16 + quad * 4 + r;
            const int n64 = nh + nl;
            const float val = (n64 >= m) ? sA[nt][r] * pwl[n64 - m] : 0.f;
            Sb[nl * 136 + m] = (_Float16)val;
        }
    }
    // Q'' columns 64..127 (even waves)
    if ((w & 1) == 0) {
        const float g = pwl[nh + mtile * 16 + l15 + 1];
#pragma unroll
        for (int ks = 0; ks < 2; ++ks) {
            f16x8 qv;
#pragma unroll
            for (int j = 0; j < 8; ++j)
                qv[j] = (_Float16)((float)aQ[ks][j] * g);
            *(f16x8*)&Sb[(mtile * 16 + l15) * 136 + 64 + ks * 32 + quad * 8] = qv;
        }
    }
    __syncthreads();

    // phase B: out = S2 @ [V ; T~]
    f32x4 oA[2] = {(f32x4){0.f,0.f,0.f,0.f}, (f32x4){0.f,0.f,0.f,0.f}};
#pragma unroll
    for (int ks = 0; ks < 4; ++ks) {
        const f16x8 aS = *(const f16x8*)&Sb[(mtile * 16 + l15) * 136 +
                                            ks * 32 + quad * 8];
#pragma unroll
        for (int nt = 0; nt < 2; ++nt) {
            const int dp = (npair + nt) * 16 + l15;
            f16x8 bV;
            if (ks < 2) {
#pragma unroll
                for (int j = 0; j < 8; ++j)
                    bV[j] = Vl[(ks * 32 + quad * 8 + j) * 72 + dp];
            } else {
#pragma unroll
                for (int j = 0; j < 8; ++j)
                    bV[j] = (_Float16)Tl[((ks - 2) * 32 + quad * 8 + j) * 68 + dp];
            }
            oA[nt] = __builtin_amdgcn_mfma_f32_16x16x32_f16(aS, bV, oA[nt], 0, 0, 0);
        }
    }
#pragma unroll
    for (int nt = 0; nt < 2; ++nt)
#pragma unroll
        for (int r = 0; r < 4; ++r)
            out[(rowbase + mtile * 16 + quad * 4 + r) * DD +
                (npair + nt) * 16 + l15] = oA[nt][r];
}

// ---------------------------------------------------------------------------
extern "C" void kernel_launch(void* const* d_in, const int* in_sizes, int n_in,
                              void* d_out, int out_size, void* d_ws, size_t ws_size,
                              hipStream_t stream)
{
    const float* X  = (const float*)d_in[0];
    const float* WQ = (const float*)d_in[1];
    const float* WK = (const float*)d_in[2];
    const float* WV = (const float*)d_in[3];
    float* outp = (float*)d_out;

    _Float16* Whg = (_Float16*)d_ws;                 // 196608 h
    _Float16* Wlg = Whg + 196608;                    // 196608 h
    _Float16* Qr  = Wlg + 196608;                    // 524288 h
    _Float16* Kr  = Qr + (size_t)BLROWS * DD;        // 524288 h
    _Float16* Vr  = Kr + (size_t)BLROWS * DD;        // 524288 h
    float*    U   = (float*)(Vr + (size_t)BLROWS * DD);   // 524288 f
    // total ~6.0 MB

    hipLaunchKernelGGL(prep_w, dim3(96), dim3(256), 0, stream,
                       WQ, WK, WV, Whg, Wlg);
    hipLaunchKernelGGL(proj_mfma, dim3(768), dim3(256), 0, stream,
                       X, Whg, Wlg, Qr, Kr, Vr);
    hipLaunchKernelGGL(chunk_kv, dim3(2 * NCHT), dim3(256), 0, stream, Kr, Vr, U);
    hipLaunchKernelGGL(chunk_out, dim3(2 * NCHT), dim3(256), 0, stream,
                       Qr, Kr, Vr, U, outp);
}